// Round 6
// baseline (6867.959 us; speedup 1.0000x reference)
//
#include <hip/hip_runtime.h>

#define Bn 512
#define Tn 256
#define Fn 128
#define Hn 512
#define KIE32 40  // 640/16 k-iters (encoder, 32x32x16)
#define KID32 32  // 512/16 k-iters (decoder)
#define EH 20     // enc k-iters per wave (k-split half)
#define DH 16     // dec k-iters per wave
#define KID 16    // y-path: 512/32 k-iters (16x16x32)
#define NWG 256
#define RS 648    // A_lds row stride in ushorts (16B-aligned, bank-optimal)

typedef __attribute__((ext_vector_type(8))) __bf16 bf16x8;
typedef __attribute__((ext_vector_type(4))) float floatx4;
typedef __attribute__((ext_vector_type(16))) float floatx16;
typedef __attribute__((ext_vector_type(4))) unsigned uintx4;

__device__ __forceinline__ unsigned short f2bf_u16(float f) {
  union { float f; unsigned u; } v; v.f = f;
  unsigned r = v.u + 0x7FFFu + ((v.u >> 16) & 1u);   // RNE
  return (unsigned short)(r >> 16);
}

__device__ __forceinline__ float sigm(float x) {
  return __builtin_amdgcn_rcpf(1.f + __expf(-x));
}
__device__ __forceinline__ float ftanh(float x) {
  return 1.f - 2.f * __builtin_amdgcn_rcpf(1.f + __expf(2.f * x));
}

// ---- pack encoder weights [x|h] -> 32x32x16 B-fragment order ----
// [nt32(64)][ki(40)][lane][8] : n = nt32*32+(l&31), k = ki*16+(l>>5)*8+j
__global__ void pack_enc_k(const float* __restrict__ Wih, const float* __restrict__ Whh,
                           unsigned short* __restrict__ Bpe) {
  int id = blockIdx.x;              // nt32*KIE32 + ki
  int nt = id / KIE32, ki = id % KIE32;
  int l = threadIdx.x;
  int n = nt * 32 + (l & 31);
  int kb = ki * 16 + (l >> 5) * 8;
  __align__(16) unsigned short o[8];
#pragma unroll
  for (int j = 0; j < 8; ++j) {
    int k = kb + j;
    float v = (k < Fn) ? Wih[n * Fn + k] : Whh[n * Hn + (k - Fn)];
    o[j] = f2bf_u16(v);
  }
  *(uint4*)(Bpe + (size_t)(id * 64 + l) * 8) = *(uint4*)o;
}

// ---- pack decoder combined weights (W_hh + W_ih@Wo) -> 32x32 frag order ----
__global__ void pack_dec_k(const float* __restrict__ Wih, const float* __restrict__ Whh,
                           const float* __restrict__ Wo, unsigned short* __restrict__ Bpd) {
  int id = blockIdx.x;              // nt32*KID32 + ki
  int nt = id / KID32, ki = id % KID32;
  int l = threadIdx.x;
  int n = nt * 32 + (l & 31);
  int kb = ki * 16 + (l >> 5) * 8;
  float acc[8];
#pragma unroll
  for (int j = 0; j < 8; ++j) acc[j] = Whh[n * Hn + kb + j];
  for (int f = 0; f < Fn; ++f) {
    float wf = Wih[n * Fn + f];
    const float* wo = Wo + f * Hn + kb;
#pragma unroll
    for (int j = 0; j < 8; ++j) acc[j] += wf * wo[j];
  }
  __align__(16) unsigned short o[8];
#pragma unroll
  for (int j = 0; j < 8; ++j) o[j] = f2bf_u16(acc[j]);
  *(uint4*)(Bpd + (size_t)(id * 64 + l) * 8) = *(uint4*)o;
}

// ---- pack Wo (y = h@Wo.T) -> 16x16x32 fragment order (UNCHANGED shape) ----
__global__ void pack_wo_k(const float* __restrict__ Wo, unsigned short* __restrict__ Bpw) {
  int id = blockIdx.x;              // ft*KID + ki
  int ft = id / KID, ki = id % KID;
  int l = threadIdx.x;
  int f = ft * 16 + (l & 15);
  int kb = ki * 32 + (l >> 4) * 8;
  __align__(16) unsigned short o[8];
#pragma unroll
  for (int j = 0; j < 8; ++j) o[j] = f2bf_u16(Wo[f * Hn + kb + j]);
  *(uint4*)(Bpw + (size_t)(id * 64 + l) * 8) = *(uint4*)o;
}

// ---- biases ----
__global__ void bias_k(const float* __restrict__ ebih, const float* __restrict__ ebhh,
                       const float* __restrict__ dbih, const float* __restrict__ dbhh,
                       const float* __restrict__ dWih, const float* __restrict__ bo,
                       float* __restrict__ benc, float* __restrict__ bdec) {
  int n = blockIdx.x * blockDim.x + threadIdx.x;  // 2048
  benc[n] = ebih[n] + ebhh[n];
  float a = dbih[n] + dbhh[n];
  for (int f = 0; f < Fn; ++f) a += dWih[n * Fn + f] * bo[f];
  bdec[n] = a;
}

// ---- pack x: ts[b][s][k] fp32 -> xp[s][b][k] bf16 ----
__global__ void pack_x_k(const float* __restrict__ ts, unsigned short* __restrict__ xp) {
  size_t i = (size_t)blockIdx.x * 256 + threadIdx.x;   // quad index
  int k4 = (int)(i & 31);
  size_t bs = i >> 5;
  int s = (int)(bs & 255);
  size_t b = bs >> 8;
  float4 v = *(const float4*)(ts + (i << 2));
  __align__(8) unsigned short o[4];
  o[0] = f2bf_u16(v.x); o[1] = f2bf_u16(v.y); o[2] = f2bf_u16(v.z); o[3] = f2bf_u16(v.w);
  *(unsigned long long*)(xp + ((size_t)s * Bn + b) * Fn + k4 * 4) = *(unsigned long long*)o;
}

// ---- init: zero Hg buffer 0 + flags + XCC sentinels ----
__global__ void init_k(unsigned long long* __restrict__ Hg0,
                       unsigned* __restrict__ flgA, unsigned* __restrict__ flgB,
                       unsigned* __restrict__ xcdP) {
  int i = blockIdx.x * 256 + threadIdx.x;   // 65536
  Hg0[i] = 0ULL;
  if (i < 8192) { flgA[i] = 0u; flgB[i] = 0u; }
  if (i < NWG) xcdP[i] = 0xFFu;             // sentinel (overlays out[0..255])
}

// Flag protocol: PROVEN baseline only (sc1 / LLC, agent scope).
#define POLL(F, p) do { \
  if (l < 16) { \
    const unsigned* fp_ = (F) + (size_t)(mg * 16 + l) * 32; \
    while (__hip_atomic_load(fp_, __ATOMIC_RELAXED, __HIP_MEMORY_SCOPE_AGENT) < (unsigned)(p)) \
      __builtin_amdgcn_s_sleep(1); \
  } \
  __asm__ __volatile__("" ::: "memory"); \
} while (0)

#define SETF(F, p) do { if (tid == 0) \
  __hip_atomic_store((F) + (size_t)gid * 32, (unsigned)(p), __ATOMIC_RELAXED, __HIP_MEMORY_SCOPE_AGENT); \
} while (0)

// h loads, 32 rows, 64B/thread: loc==1 -> sc0 (this XCD's L2); else sc1.
#define STAGE_H2(OFF, curbuf) do { \
  const unsigned short* sp_ = Hg + (size_t)(curbuf) * (Bn * Hn) + (size_t)(b0 + sh_r) * Hn + sh_c * 32; \
  uintx4 t0_, t1_, t2_, t3_; \
  if (loc) { \
    asm volatile("global_load_dwordx4 %0, %4, off sc0\n\t" \
                 "global_load_dwordx4 %1, %4, off offset:16 sc0\n\t" \
                 "global_load_dwordx4 %2, %4, off offset:32 sc0\n\t" \
                 "global_load_dwordx4 %3, %4, off offset:48 sc0\n\t" \
                 "s_waitcnt vmcnt(0)" \
                 : "=&v"(t0_), "=&v"(t1_), "=&v"(t2_), "=&v"(t3_) : "v"(sp_) : "memory"); \
  } else { \
    const unsigned long long* src_ = (const unsigned long long*)sp_; \
    unsigned long long v_[8]; \
    _Pragma("unroll") for (int u_ = 0; u_ < 8; ++u_) \
      v_[u_] = __hip_atomic_load(src_ + u_, __ATOMIC_RELAXED, __HIP_MEMORY_SCOPE_AGENT); \
    t0_[0] = (unsigned)v_[0]; t0_[1] = (unsigned)(v_[0] >> 32); t0_[2] = (unsigned)v_[1]; t0_[3] = (unsigned)(v_[1] >> 32); \
    t1_[0] = (unsigned)v_[2]; t1_[1] = (unsigned)(v_[2] >> 32); t1_[2] = (unsigned)v_[3]; t1_[3] = (unsigned)(v_[3] >> 32); \
    t2_[0] = (unsigned)v_[4]; t2_[1] = (unsigned)(v_[4] >> 32); t2_[2] = (unsigned)v_[5]; t2_[3] = (unsigned)(v_[5] >> 32); \
    t3_[0] = (unsigned)v_[6]; t3_[1] = (unsigned)(v_[6] >> 32); t3_[2] = (unsigned)v_[7]; t3_[3] = (unsigned)(v_[7] >> 32); \
  } \
  uintx4* dst_ = (uintx4*)&A_lds[sh_r * RS + (OFF) + sh_c * 32]; \
  dst_[0] = t0_; dst_[1] = t1_; dst_[2] = t2_; dst_[3] = t3_; \
} while (0)

#define STAGE_X2(s_) do { \
  uint4 xv_ = *(const uint4*)(xp + ((size_t)(s_) * Bn + b0 + sh_r) * Fn + sh_c * 8); \
  *(uint4*)&A_lds[sh_r * RS + sh_c * 8] = xv_; \
} while (0)

// 32x32x16 gate MFMA: wave = (gate g2, k-half kh). A-read 1KB/k-iter (2x FLOP
// per A-byte vs 16x16x32). Partials summed cross-wave via ds_add_f32 into
// zeroed gates_lds; EPI reads + re-zeros (barrier-ordered).
#define MFMA_G32(BR, KN) do { \
  floatx16 a_ = {0.f}; \
  const unsigned short* Ar_ = &A_lds[l31 * RS + (kh * (KN)) * 16 + ksub]; \
  _Pragma("unroll") for (int t = 0; t < (KN); ++t) \
    a_ = __builtin_amdgcn_mfma_f32_32x32x16_bf16(*(const bf16x8*)(Ar_ + t * 16), (BR)[t], a_, 0, 0, 0); \
  _Pragma("unroll") for (int r = 0; r < 16; ++r) { \
    int row_ = (r & 3) + 8 * (r >> 2) + 4 * lhi; \
    __hip_atomic_fetch_add(&gates_lds[g2][row_][l31], a_[r], __ATOMIC_RELAXED, __HIP_MEMORY_SCOPE_WORKGROUP); \
  } \
} while (0)

// decoder y (16x16x32, unchanged math): waves 3 (rows 0-15) / 7 (rows 16-31)
#define MFMA_Y(sd) do { \
  floatx4 ay_ = {0.f, 0.f, 0.f, 0.f}; \
  const unsigned short* Ay_ = &A_lds[(l15 + yro) * RS + q * 8]; \
  _Pragma("unroll") for (int k = 0; k < KID; ++k) \
    ay_ = __builtin_amdgcn_mfma_f32_16x16x32_bf16( \
        *(const bf16x8*)(Ay_ + k * 32), *(const bf16x8*)&Bw_lds[(k * 64 + l) * 8], ay_, 0, 0, 0); \
  _Pragma("unroll") for (int r = 0; r < 4; ++r) \
    __builtin_nontemporal_store(ay_[r] + bof, \
      out + ((size_t)(b0 + yro + q * 4 + r) * Tn + (Tn - 1 - (sd))) * Fn + ns * 16 + l15); \
} while (0)

// epilogue: 2 rows/thread (eb -> cA, eb+16 -> cB), col ej; re-zeros gates_lds
#define EPI2(BI, BF, BG, BO, nxtbuf) do { \
  float gi0_ = gates_lds[0][eb][ej] + (BI); \
  float gf0_ = gates_lds[1][eb][ej] + (BF); \
  float gg0_ = gates_lds[2][eb][ej] + (BG); \
  float go0_ = gates_lds[3][eb][ej] + (BO); \
  float gi1_ = gates_lds[0][eb + 16][ej] + (BI); \
  float gf1_ = gates_lds[1][eb + 16][ej] + (BF); \
  float gg1_ = gates_lds[2][eb + 16][ej] + (BG); \
  float go1_ = gates_lds[3][eb + 16][ej] + (BO); \
  gates_lds[0][eb][ej] = 0.f; gates_lds[1][eb][ej] = 0.f; \
  gates_lds[2][eb][ej] = 0.f; gates_lds[3][eb][ej] = 0.f; \
  gates_lds[0][eb + 16][ej] = 0.f; gates_lds[1][eb + 16][ej] = 0.f; \
  gates_lds[2][eb + 16][ej] = 0.f; gates_lds[3][eb + 16][ej] = 0.f; \
  cA = sigm(gf0_) * cA + sigm(gi0_) * ftanh(gg0_); \
  float h0_ = sigm(go0_) * ftanh(cA); \
  cB = sigm(gf1_) * cB + sigm(gi1_) * ftanh(gg1_); \
  float h1_ = sigm(go1_) * ftanh(cB); \
  unsigned short hv0_ = f2bf_u16(h0_), hv1_ = f2bf_u16(h1_); \
  unsigned short* hp0_ = Hg + (size_t)(nxtbuf) * (Bn * Hn) + (size_t)(b0 + eb) * Hn + j0 + ej; \
  unsigned short* hp1_ = hp0_ + 16 * Hn; \
  if (loc) { *hp0_ = hv0_; *hp1_ = hv1_; } \
  else { \
    __hip_atomic_store(hp0_, hv0_, __ATOMIC_RELAXED, __HIP_MEMORY_SCOPE_AGENT); \
    __hip_atomic_store(hp1_, hv1_, __ATOMIC_RELAXED, __HIP_MEMORY_SCOPE_AGENT); \
  } \
} while (0)

// ---- persistent LSTM enc-dec: 256 wgs x 512 thr, 32x32x16 gate MFMA ----
__global__ __launch_bounds__(512, 2) void lstm_persist(
    const unsigned short* __restrict__ xp,
    const unsigned short* __restrict__ Bpe,
    const unsigned short* __restrict__ Bpd,
    const unsigned short* __restrict__ Bpw,
    const float* __restrict__ benc,
    const float* __restrict__ bdec,
    const float* __restrict__ bo,
    unsigned short* __restrict__ Hg,   // [2][512][512] bf16
    unsigned* __restrict__ flgA,
    unsigned* __restrict__ flgB,
    unsigned* __restrict__ xcdPub,     // [256] published XCC ids (overlays out)
    float* __restrict__ out)           // [512][256][128] fp32
{
  const int wg = blockIdx.x;
  const int tid = threadIdx.x;
  const int w = tid >> 6, l = tid & 63;
  const int l15 = l & 15, q = l >> 4;        // 16x16 y-path indices
  const int l31 = l & 31, lhi = l >> 5;      // 32x32 fragment indices
  const int g2 = w & 3, kh = w >> 2;         // wave = (gate, k-half)
  const int ksub = lhi * 8;                  // k sub-offset within k-iter
  const int eb = tid >> 5, ej = tid & 31;    // epilogue (rows eb, eb+16; col ej)
  const int sh_r = tid >> 4, sh_c = tid & 15;// staging (row 0..31, col chunk)

  // bijective relabel assuming round-robin XCD dispatch: XCD = wg & 7
  const int grp = wg & 7, rank = wg >> 3;
  const int mg = grp * 2 + (rank >> 4);
  const int ns = rank & 15;
  const int gid = mg * 16 + ns;
  const int b0 = mg * 32, j0 = ns * 32;

  __shared__ __align__(16) unsigned short A_lds[32 * RS];        // 41.5 KB
  __shared__ __align__(16) float gates_lds[4][32][33];           // 16.9 KB
  __shared__ __align__(16) unsigned short Bw_lds[KID * 64 * 8];  // 16.4 KB
  __shared__ int sh_asn[2];

  // ---- publish my XCC id; bounded group-local locality verification ----
  if (tid == 0) {
    unsigned x_;
    asm volatile("s_getreg_b32 %0, hwreg(HW_REG_XCC_ID)" : "=s"(x_));
    x_ &= 15u;
    sh_asn[1] = (int)x_;
    __hip_atomic_store(&xcdPub[wg], x_, __ATOMIC_RELAXED, __HIP_MEMORY_SCOPE_AGENT);
  }
  __syncthreads();
  const unsigned myx = (unsigned)sh_asn[1];
  if (tid < 64) {
    int ok = 1;
    if (tid < 16) {
      const int phys = grp + 8 * ((mg & 1) * 16 + tid);
      unsigned v_ = 0xFFu;
      for (int it = 0; it < 32768; ++it) {   // bounded: cannot hang
        v_ = __hip_atomic_load(&xcdPub[phys], __ATOMIC_RELAXED, __HIP_MEMORY_SCOPE_AGENT);
        if (v_ != 0xFFu) break;
        __builtin_amdgcn_s_sleep(2);
      }
      ok = (v_ == myx) ? 1 : 0;
    }
    int all_ = __all(ok) ? 1 : 0;
    if (tid == 0) sh_asn[0] = all_;
  }
  __syncthreads();
  const int loc = sh_asn[0];                 // group-uniform

  // ---- preload B tiles: (20+16)*4 = 144 VGPRs ----
  bf16x8 Bq[EH], Bd[DH];
  const int nt32 = g2 * 16 + ns;
  {
    const bf16x8* p = (const bf16x8*)Bpe + ((size_t)nt32 * KIE32 + kh * EH) * 64 + l;
#pragma unroll
    for (int k = 0; k < EH; ++k) Bq[k] = p[k * 64];
  }
  {
    const bf16x8* p = (const bf16x8*)Bpd + ((size_t)nt32 * KID32 + kh * DH) * 64 + l;
#pragma unroll
    for (int k = 0; k < DH; ++k) Bd[k] = p[k * 64];
  }
  // per-thread gate biases (EPI uses col j0+ej)
  const float bie = benc[0 * Hn + j0 + ej], bfe = benc[1 * Hn + j0 + ej];
  const float bge = benc[2 * Hn + j0 + ej], boe = benc[3 * Hn + j0 + ej];
  const float bid = bdec[0 * Hn + j0 + ej], bfd = bdec[1 * Hn + j0 + ej];
  const float bgd = bdec[2 * Hn + j0 + ej], bod = bdec[3 * Hn + j0 + ej];

  if (ns < 8) { // constant Wo slice -> LDS, once
    const uint4* src = (const uint4*)(Bpw + (size_t)ns * (KID * 64 * 8));
    uint4* dst = (uint4*)Bw_lds;
    dst[tid * 2] = src[tid * 2];
    dst[tid * 2 + 1] = src[tid * 2 + 1];
  }
  const bool doY = (ns < 8) && (g2 == 3);    // waves 3 (kh0) and 7 (kh1)
  const int yro = kh ? 16 : 0;
  float bof = 0.f;
  if (doY) bof = bo[ns * 16 + l15];

  // zero the gate accumulation buffer once (EPI re-zeros each step)
  for (int i = tid; i < 4 * 32 * 33; i += 512) ((float*)gates_lds)[i] = 0.f;

  float cA = 0.f, cB = 0.f;

  __syncthreads();                   // Bw_lds + gates zero ready

  // ================= encoder =================
  for (int s = 0; s < Tn; ++s) {
    const int cur = s & 1, nxt = cur ^ 1;
    POLL(flgA, s);                   // all members: h(s-1) visible, buffers safe
    STAGE_X2(s);
    STAGE_H2(Fn, cur);
    __syncthreads();                 // A staged
    MFMA_G32(Bq, EH);
    __syncthreads();                 // both k-half partials summed in LDS
    EPI2(bie, bfe, bge, boe, nxt);
    __syncthreads();                 // drains EPI h stores (vmcnt0 at barrier)
    SETF(flgA, s + 1);
  }

  // ================= decoder =================
  cA = 0.f; cB = 0.f;                // reference restarts c at zero
  for (int sd = 0; sd < Tn; ++sd) {
    const int phg = Tn + sd;
    const int cur = phg & 1, nxt = cur ^ 1;
    POLL(flgA, phg);
    STAGE_H2(0, cur);
    __syncthreads();
    MFMA_G32(Bd, DH);
    if (doY) MFMA_Y(sd);
    __syncthreads();
    EPI2(bid, bfd, bgd, bod, nxt);
    __syncthreads();
    SETF(flgA, phg + 1);
  }
}

extern "C" void kernel_launch(void* const* d_in, const int* in_sizes, int n_in,
                              void* d_out, int out_size, void* d_ws, size_t ws_size,
                              hipStream_t stream) {
  const float* ts   = (const float*)d_in[0];
  const float* eWih = (const float*)d_in[1];
  const float* eWhh = (const float*)d_in[2];
  const float* ebih = (const float*)d_in[3];
  const float* ebhh = (const float*)d_in[4];
  const float* dWih = (const float*)d_in[5];
  const float* dWhh = (const float*)d_in[6];
  const float* dbih = (const float*)d_in[7];
  const float* dbhh = (const float*)d_in[8];
  const float* Wo   = (const float*)d_in[9];
  const float* bo   = (const float*)d_in[10];
  float* outp = (float*)d_out;

  char* ws = (char*)d_ws;
  unsigned short* Bpe  = (unsigned short*)(ws);                 // 2,621,440 B
  unsigned short* Bpd  = (unsigned short*)(ws + 2621440);       // 2,097,152 B
  unsigned short* Bpw  = (unsigned short*)(ws + 4718592);       //   131,072 B
  float*          benc = (float*)(ws + 4849664);                //     8,192 B
  float*          bdec = (float*)(ws + 4857856);                //     8,192 B
  unsigned short* Hg   = (unsigned short*)(ws + 4866048);       // 1,048,576 B
  unsigned*       flgA = (unsigned*)(ws + 5914624);             //    32,768 B
  unsigned*       flgB = (unsigned*)(ws + 5947392);             //    32,768 B
  unsigned short* xp   = (unsigned short*)(ws + 5980160);       // 16,777,216 B
  unsigned*       xcdP = (unsigned*)outp;   // scratch overlay; decoder rewrites
                                            // out[0..255] only at sd>=254,
                                            // strictly after all reads of it

  pack_enc_k<<<64 * KIE32, 64, 0, stream>>>(eWih, eWhh, Bpe);
  pack_dec_k<<<64 * KID32, 64, 0, stream>>>(dWih, dWhh, Wo, Bpd);
  pack_wo_k<<<8 * KID, 64, 0, stream>>>(Wo, Bpw);
  bias_k<<<8, 256, 0, stream>>>(ebih, ebhh, dbih, dbhh, dWih, bo, benc, bdec);
  pack_x_k<<<16384, 256, 0, stream>>>(ts, xp);
  init_k<<<256, 256, 0, stream>>>((unsigned long long*)Hg, flgA, flgB, xcdP);

  lstm_persist<<<NWG, 512, 0, stream>>>(xp, Bpe, Bpd, Bpw, benc, bdec, bo, Hg,
                                        flgA, flgB, xcdP, outp);
}

// Round 7
// 1742.279 us; speedup vs baseline: 3.9419x; 3.9419x over previous
//
#include <hip/hip_runtime.h>

#define Bn 512
#define Tn 256
#define Fn 128
#define Hn 512
#define KIE32 40  // 640/16 k-iters (encoder, 32x32x16)
#define KID32 32  // 512/16 k-iters (decoder)
#define EH 20     // enc k-iters per wave (k-split half)
#define DH 16     // dec k-iters per wave
#define KID 16    // y-path: 512/32 k-iters (16x16x32)
#define NWG 256
#define RS 648    // A_lds row stride in ushorts (16B-aligned)

typedef __attribute__((ext_vector_type(8))) __bf16 bf16x8;
typedef __attribute__((ext_vector_type(4))) float floatx4;
typedef __attribute__((ext_vector_type(16))) float floatx16;
typedef __attribute__((ext_vector_type(4))) unsigned uintx4;

__device__ __forceinline__ unsigned short f2bf_u16(float f) {
  union { float f; unsigned u; } v; v.f = f;
  unsigned r = v.u + 0x7FFFu + ((v.u >> 16) & 1u);   // RNE
  return (unsigned short)(r >> 16);
}

__device__ __forceinline__ float sigm(float x) {
  return __builtin_amdgcn_rcpf(1.f + __expf(-x));
}
__device__ __forceinline__ float ftanh(float x) {
  return 1.f - 2.f * __builtin_amdgcn_rcpf(1.f + __expf(2.f * x));
}

// ---- pack encoder weights [x|h] -> 32x32x16 B-fragment order ----
__global__ void pack_enc_k(const float* __restrict__ Wih, const float* __restrict__ Whh,
                           unsigned short* __restrict__ Bpe) {
  int id = blockIdx.x;              // nt32*KIE32 + ki
  int nt = id / KIE32, ki = id % KIE32;
  int l = threadIdx.x;
  int n = nt * 32 + (l & 31);
  int kb = ki * 16 + (l >> 5) * 8;
  __align__(16) unsigned short o[8];
#pragma unroll
  for (int j = 0; j < 8; ++j) {
    int k = kb + j;
    float v = (k < Fn) ? Wih[n * Fn + k] : Whh[n * Hn + (k - Fn)];
    o[j] = f2bf_u16(v);
  }
  *(uint4*)(Bpe + (size_t)(id * 64 + l) * 8) = *(uint4*)o;
}

// ---- pack decoder combined weights (W_hh + W_ih@Wo) -> 32x32 frag order ----
__global__ void pack_dec_k(const float* __restrict__ Wih, const float* __restrict__ Whh,
                           const float* __restrict__ Wo, unsigned short* __restrict__ Bpd) {
  int id = blockIdx.x;              // nt32*KID32 + ki
  int nt = id / KID32, ki = id % KID32;
  int l = threadIdx.x;
  int n = nt * 32 + (l & 31);
  int kb = ki * 16 + (l >> 5) * 8;
  float acc[8];
#pragma unroll
  for (int j = 0; j < 8; ++j) acc[j] = Whh[n * Hn + kb + j];
  for (int f = 0; f < Fn; ++f) {
    float wf = Wih[n * Fn + f];
    const float* wo = Wo + f * Hn + kb;
#pragma unroll
    for (int j = 0; j < 8; ++j) acc[j] += wf * wo[j];
  }
  __align__(16) unsigned short o[8];
#pragma unroll
  for (int j = 0; j < 8; ++j) o[j] = f2bf_u16(acc[j]);
  *(uint4*)(Bpd + (size_t)(id * 64 + l) * 8) = *(uint4*)o;
}

// ---- pack Wo (y = h@Wo.T) -> 16x16x32 fragment order ----
__global__ void pack_wo_k(const float* __restrict__ Wo, unsigned short* __restrict__ Bpw) {
  int id = blockIdx.x;              // ft*KID + ki
  int ft = id / KID, ki = id % KID;
  int l = threadIdx.x;
  int f = ft * 16 + (l & 15);
  int kb = ki * 32 + (l >> 4) * 8;
  __align__(16) unsigned short o[8];
#pragma unroll
  for (int j = 0; j < 8; ++j) o[j] = f2bf_u16(Wo[f * Hn + kb + j]);
  *(uint4*)(Bpw + (size_t)(id * 64 + l) * 8) = *(uint4*)o;
}

// ---- biases ----
__global__ void bias_k(const float* __restrict__ ebih, const float* __restrict__ ebhh,
                       const float* __restrict__ dbih, const float* __restrict__ dbhh,
                       const float* __restrict__ dWih, const float* __restrict__ bo,
                       float* __restrict__ benc, float* __restrict__ bdec) {
  int n = blockIdx.x * blockDim.x + threadIdx.x;  // 2048
  benc[n] = ebih[n] + ebhh[n];
  float a = dbih[n] + dbhh[n];
  for (int f = 0; f < Fn; ++f) a += dWih[n * Fn + f] * bo[f];
  bdec[n] = a;
}

// ---- pack x: ts[b][s][k] fp32 -> xp[s][b][k] bf16 ----
__global__ void pack_x_k(const float* __restrict__ ts, unsigned short* __restrict__ xp) {
  size_t i = (size_t)blockIdx.x * 256 + threadIdx.x;   // quad index
  int k4 = (int)(i & 31);
  size_t bs = i >> 5;
  int s = (int)(bs & 255);
  size_t b = bs >> 8;
  float4 v = *(const float4*)(ts + (i << 2));
  __align__(8) unsigned short o[4];
  o[0] = f2bf_u16(v.x); o[1] = f2bf_u16(v.y); o[2] = f2bf_u16(v.z); o[3] = f2bf_u16(v.w);
  *(unsigned long long*)(xp + ((size_t)s * Bn + b) * Fn + k4 * 4) = *(unsigned long long*)o;
}

// ---- init: zero Hg buffer 0 + flags + XCC sentinels ----
__global__ void init_k(unsigned long long* __restrict__ Hg0,
                       unsigned* __restrict__ flgA, unsigned* __restrict__ flgB,
                       unsigned* __restrict__ xcdP) {
  int i = blockIdx.x * 256 + threadIdx.x;   // 65536
  Hg0[i] = 0ULL;
  if (i < 8192) { flgA[i] = 0u; flgB[i] = 0u; }
  if (i < NWG) xcdP[i] = 0xFFu;             // sentinel (overlays out[0..255])
}

// Flag protocol: PROVEN baseline only (sc1 / LLC, agent scope).
#define POLL(F, p) do { \
  if (l < 16) { \
    const unsigned* fp_ = (F) + (size_t)(mg * 16 + l) * 32; \
    while (__hip_atomic_load(fp_, __ATOMIC_RELAXED, __HIP_MEMORY_SCOPE_AGENT) < (unsigned)(p)) \
      __builtin_amdgcn_s_sleep(1); \
  } \
  __asm__ __volatile__("" ::: "memory"); \
} while (0)

#define SETF(F, p) do { if (tid == 0) \
  __hip_atomic_store((F) + (size_t)gid * 32, (unsigned)(p), __ATOMIC_RELAXED, __HIP_MEMORY_SCOPE_AGENT); \
} while (0)

// h loads, 32 rows, 64B/thread: loc==1 -> sc0 (this XCD's L2); else sc1.
#define STAGE_H2(OFF, curbuf) do { \
  const unsigned short* sp_ = Hg + (size_t)(curbuf) * (Bn * Hn) + (size_t)(b0 + sh_r) * Hn + sh_c * 32; \
  uintx4 t0_, t1_, t2_, t3_; \
  if (loc) { \
    asm volatile("global_load_dwordx4 %0, %4, off sc0\n\t" \
                 "global_load_dwordx4 %1, %4, off offset:16 sc0\n\t" \
                 "global_load_dwordx4 %2, %4, off offset:32 sc0\n\t" \
                 "global_load_dwordx4 %3, %4, off offset:48 sc0\n\t" \
                 "s_waitcnt vmcnt(0)" \
                 : "=&v"(t0_), "=&v"(t1_), "=&v"(t2_), "=&v"(t3_) : "v"(sp_) : "memory"); \
  } else { \
    const unsigned long long* src_ = (const unsigned long long*)sp_; \
    unsigned long long v_[8]; \
    _Pragma("unroll") for (int u_ = 0; u_ < 8; ++u_) \
      v_[u_] = __hip_atomic_load(src_ + u_, __ATOMIC_RELAXED, __HIP_MEMORY_SCOPE_AGENT); \
    t0_[0] = (unsigned)v_[0]; t0_[1] = (unsigned)(v_[0] >> 32); t0_[2] = (unsigned)v_[1]; t0_[3] = (unsigned)(v_[1] >> 32); \
    t1_[0] = (unsigned)v_[2]; t1_[1] = (unsigned)(v_[2] >> 32); t1_[2] = (unsigned)v_[3]; t1_[3] = (unsigned)(v_[3] >> 32); \
    t2_[0] = (unsigned)v_[4]; t2_[1] = (unsigned)(v_[4] >> 32); t2_[2] = (unsigned)v_[5]; t2_[3] = (unsigned)(v_[5] >> 32); \
    t3_[0] = (unsigned)v_[6]; t3_[1] = (unsigned)(v_[6] >> 32); t3_[2] = (unsigned)v_[7]; t3_[3] = (unsigned)(v_[7] >> 32); \
  } \
  uintx4* dst_ = (uintx4*)&A_lds[sh_r * RS + (OFF) + sh_c * 32]; \
  dst_[0] = t0_; dst_[1] = t1_; dst_[2] = t2_; dst_[3] = t3_; \
} while (0)

#define STAGE_X2(s_) do { \
  uint4 xv_ = *(const uint4*)(xp + ((size_t)(s_) * Bn + b0 + sh_r) * Fn + sh_c * 8); \
  *(uint4*)&A_lds[sh_r * RS + sh_c * 8] = xv_; \
} while (0)

// decoder y (16x16x32): waves g2==3 (kh0: rows 0-15, kh1: rows 16-31)
#define MFMA_Y(sd) do { \
  floatx4 ay_ = {0.f, 0.f, 0.f, 0.f}; \
  const unsigned short* Ay_ = &A_lds[(l15 + yro) * RS + q * 8]; \
  _Pragma("unroll") for (int k = 0; k < KID; ++k) \
    ay_ = __builtin_amdgcn_mfma_f32_16x16x32_bf16( \
        *(const bf16x8*)(Ay_ + k * 32), *(const bf16x8*)&Bw_lds[(k * 64 + l) * 8], ay_, 0, 0, 0); \
  _Pragma("unroll") for (int r = 0; r < 4; ++r) \
    __builtin_nontemporal_store(ay_[r] + bof, \
      out + ((size_t)(b0 + yro + q * 4 + r) * Tn + (Tn - 1 - (sd))) * Fn + ns * 16 + l15); \
} while (0)

// 32x32x16 gate MFMA with barrier-ordered 2-pass k-half reduction (NO atomics):
// all waves compute partial in regs; kh=1 STORES into gates_lds (overwrite);
// barrier; kh=0 reads, adds its partial, stores final. y overlaps pre-barrier.
#define GATES32(BR, KN, DOY, sd) do { \
  floatx16 a_ = {0.f}; \
  const unsigned short* Ar_ = &A_lds[l31 * RS + (kh * (KN)) * 16 + ksub]; \
  _Pragma("unroll") for (int t = 0; t < (KN); ++t) \
    a_ = __builtin_amdgcn_mfma_f32_32x32x16_bf16(*(const bf16x8*)(Ar_ + t * 16), (BR)[t], a_, 0, 0, 0); \
  if (kh) { \
    _Pragma("unroll") for (int r = 0; r < 16; ++r) \
      gates_lds[g2][(r & 3) + 8 * (r >> 2) + 4 * lhi][l31] = a_[r]; \
  } \
  if (DOY) MFMA_Y(sd); \
  __syncthreads(); \
  if (!kh) { \
    _Pragma("unroll") for (int r = 0; r < 16; ++r) { \
      int row_ = (r & 3) + 8 * (r >> 2) + 4 * lhi; \
      gates_lds[g2][row_][l31] += a_[r]; \
    } \
  } \
} while (0)

// epilogue: 2 rows/thread (eb -> cA, eb+16 -> cB), col ej
#define EPI2(BI, BF, BG, BO, nxtbuf) do { \
  float gi0_ = gates_lds[0][eb][ej] + (BI); \
  float gf0_ = gates_lds[1][eb][ej] + (BF); \
  float gg0_ = gates_lds[2][eb][ej] + (BG); \
  float go0_ = gates_lds[3][eb][ej] + (BO); \
  float gi1_ = gates_lds[0][eb + 16][ej] + (BI); \
  float gf1_ = gates_lds[1][eb + 16][ej] + (BF); \
  float gg1_ = gates_lds[2][eb + 16][ej] + (BG); \
  float go1_ = gates_lds[3][eb + 16][ej] + (BO); \
  cA = sigm(gf0_) * cA + sigm(gi0_) * ftanh(gg0_); \
  float h0_ = sigm(go0_) * ftanh(cA); \
  cB = sigm(gf1_) * cB + sigm(gi1_) * ftanh(gg1_); \
  float h1_ = sigm(go1_) * ftanh(cB); \
  unsigned short hv0_ = f2bf_u16(h0_), hv1_ = f2bf_u16(h1_); \
  unsigned short* hp0_ = Hg + (size_t)(nxtbuf) * (Bn * Hn) + (size_t)(b0 + eb) * Hn + j0 + ej; \
  unsigned short* hp1_ = hp0_ + 16 * Hn; \
  if (loc) { *hp0_ = hv0_; *hp1_ = hv1_; } \
  else { \
    __hip_atomic_store(hp0_, hv0_, __ATOMIC_RELAXED, __HIP_MEMORY_SCOPE_AGENT); \
    __hip_atomic_store(hp1_, hv1_, __ATOMIC_RELAXED, __HIP_MEMORY_SCOPE_AGENT); \
  } \
} while (0)

// ---- persistent LSTM enc-dec: 256 wgs x 512 thr, 32x32x16 gate MFMA ----
__global__ __launch_bounds__(512, 2) void lstm_persist(
    const unsigned short* __restrict__ xp,
    const unsigned short* __restrict__ Bpe,
    const unsigned short* __restrict__ Bpd,
    const unsigned short* __restrict__ Bpw,
    const float* __restrict__ benc,
    const float* __restrict__ bdec,
    const float* __restrict__ bo,
    unsigned short* __restrict__ Hg,   // [2][512][512] bf16
    unsigned* __restrict__ flgA,
    unsigned* __restrict__ flgB,
    unsigned* __restrict__ xcdPub,     // [256] published XCC ids (overlays out)
    float* __restrict__ out)           // [512][256][128] fp32
{
  const int wg = blockIdx.x;
  const int tid = threadIdx.x;
  const int w = tid >> 6, l = tid & 63;
  const int l15 = l & 15, q = l >> 4;        // 16x16 y-path indices
  const int l31 = l & 31, lhi = l >> 5;      // 32x32 fragment indices
  const int g2 = w & 3, kh = w >> 2;         // wave = (gate, k-half)
  const int ksub = lhi * 8;                  // k sub-offset within k-iter
  const int eb = tid >> 5, ej = tid & 31;    // epilogue (rows eb, eb+16; col ej)
  const int sh_r = tid >> 4, sh_c = tid & 15;// staging (row 0..31, col chunk)

  // bijective relabel assuming round-robin XCD dispatch: XCD = wg & 7
  const int grp = wg & 7, rank = wg >> 3;
  const int mg = grp * 2 + (rank >> 4);
  const int ns = rank & 15;
  const int gid = mg * 16 + ns;
  const int b0 = mg * 32, j0 = ns * 32;

  __shared__ __align__(16) unsigned short A_lds[32 * RS];        // 41.5 KB
  __shared__ __align__(16) float gates_lds[4][32][33];           // 16.9 KB
  __shared__ __align__(16) unsigned short Bw_lds[KID * 64 * 8];  // 16.4 KB
  __shared__ int sh_asn[2];

  // ---- publish my XCC id; bounded group-local locality verification ----
  if (tid == 0) {
    unsigned x_;
    asm volatile("s_getreg_b32 %0, hwreg(HW_REG_XCC_ID)" : "=s"(x_));
    x_ &= 15u;
    sh_asn[1] = (int)x_;
    __hip_atomic_store(&xcdPub[wg], x_, __ATOMIC_RELAXED, __HIP_MEMORY_SCOPE_AGENT);
  }
  __syncthreads();
  const unsigned myx = (unsigned)sh_asn[1];
  if (tid < 64) {
    int ok = 1;
    if (tid < 16) {
      const int phys = grp + 8 * ((mg & 1) * 16 + tid);
      unsigned v_ = 0xFFu;
      for (int it = 0; it < 32768; ++it) {   // bounded: cannot hang
        v_ = __hip_atomic_load(&xcdPub[phys], __ATOMIC_RELAXED, __HIP_MEMORY_SCOPE_AGENT);
        if (v_ != 0xFFu) break;
        __builtin_amdgcn_s_sleep(2);
      }
      ok = (v_ == myx) ? 1 : 0;
    }
    int all_ = __all(ok) ? 1 : 0;
    if (tid == 0) sh_asn[0] = all_;
  }
  __syncthreads();
  const int loc = sh_asn[0];                 // group-uniform

  // ---- preload B tiles: (20+16)*4 = 144 regs (unified VGPR/AGPR file) ----
  bf16x8 Bq[EH], Bd[DH];
  const int nt32 = g2 * 16 + ns;
  {
    const bf16x8* p = (const bf16x8*)Bpe + ((size_t)nt32 * KIE32 + kh * EH) * 64 + l;
#pragma unroll
    for (int k = 0; k < EH; ++k) Bq[k] = p[k * 64];
  }
  {
    const bf16x8* p = (const bf16x8*)Bpd + ((size_t)nt32 * KID32 + kh * DH) * 64 + l;
#pragma unroll
    for (int k = 0; k < DH; ++k) Bd[k] = p[k * 64];
  }
  // per-thread gate biases (EPI uses col j0+ej)
  const float bie = benc[0 * Hn + j0 + ej], bfe = benc[1 * Hn + j0 + ej];
  const float bge = benc[2 * Hn + j0 + ej], boe = benc[3 * Hn + j0 + ej];
  const float bid = bdec[0 * Hn + j0 + ej], bfd = bdec[1 * Hn + j0 + ej];
  const float bgd = bdec[2 * Hn + j0 + ej], bod = bdec[3 * Hn + j0 + ej];

  if (ns < 8) { // constant Wo slice -> LDS, once
    const uint4* src = (const uint4*)(Bpw + (size_t)ns * (KID * 64 * 8));
    uint4* dst = (uint4*)Bw_lds;
    dst[tid * 2] = src[tid * 2];
    dst[tid * 2 + 1] = src[tid * 2 + 1];
  }
  const bool doY = (ns < 8) && (g2 == 3);    // waves 3 (kh0) and 7 (kh1)
  const int yro = kh ? 16 : 0;
  float bof = 0.f;
  if (doY) bof = bo[ns * 16 + l15];

  float cA = 0.f, cB = 0.f;

  __syncthreads();                   // Bw_lds staged

  // ================= encoder =================
  for (int s = 0; s < Tn; ++s) {
    const int cur = s & 1, nxt = cur ^ 1;
    POLL(flgA, s);                   // all members: h(s-1) visible, buffers safe
    STAGE_X2(s);
    STAGE_H2(Fn, cur);
    __syncthreads();                 // A staged
    GATES32(Bq, EH, false, 0);       // compute + kh1-store | barrier | kh0-add
    __syncthreads();                 // gates final
    EPI2(bie, bfe, bge, boe, nxt);
    __syncthreads();                 // drains EPI h stores (vmcnt0 at barrier)
    SETF(flgA, s + 1);
  }

  // ================= decoder =================
  cA = 0.f; cB = 0.f;                // reference restarts c at zero
  for (int sd = 0; sd < Tn; ++sd) {
    const int phg = Tn + sd;
    const int cur = phg & 1, nxt = cur ^ 1;
    POLL(flgA, phg);
    STAGE_H2(0, cur);
    __syncthreads();
    GATES32(Bd, DH, doY, sd);
    __syncthreads();
    EPI2(bid, bfd, bgd, bod, nxt);
    __syncthreads();
    SETF(flgA, phg + 1);
  }
}

extern "C" void kernel_launch(void* const* d_in, const int* in_sizes, int n_in,
                              void* d_out, int out_size, void* d_ws, size_t ws_size,
                              hipStream_t stream) {
  const float* ts   = (const float*)d_in[0];
  const float* eWih = (const float*)d_in[1];
  const float* eWhh = (const float*)d_in[2];
  const float* ebih = (const float*)d_in[3];
  const float* ebhh = (const float*)d_in[4];
  const float* dWih = (const float*)d_in[5];
  const float* dWhh = (const float*)d_in[6];
  const float* dbih = (const float*)d_in[7];
  const float* dbhh = (const float*)d_in[8];
  const float* Wo   = (const float*)d_in[9];
  const float* bo   = (const float*)d_in[10];
  float* outp = (float*)d_out;

  char* ws = (char*)d_ws;
  unsigned short* Bpe  = (unsigned short*)(ws);                 // 2,621,440 B
  unsigned short* Bpd  = (unsigned short*)(ws + 2621440);       // 2,097,152 B
  unsigned short* Bpw  = (unsigned short*)(ws + 4718592);       //   131,072 B
  float*          benc = (float*)(ws + 4849664);                //     8,192 B
  float*          bdec = (float*)(ws + 4857856);                //     8,192 B
  unsigned short* Hg   = (unsigned short*)(ws + 4866048);       // 1,048,576 B
  unsigned*       flgA = (unsigned*)(ws + 5914624);             //    32,768 B
  unsigned*       flgB = (unsigned*)(ws + 5947392);             //    32,768 B
  unsigned short* xp   = (unsigned short*)(ws + 5980160);       // 16,777,216 B
  unsigned*       xcdP = (unsigned*)outp;   // scratch overlay; decoder rewrites
                                            // out[0..255] only at sd>=254,
                                            // strictly after all reads of it

  pack_enc_k<<<64 * KIE32, 64, 0, stream>>>(eWih, eWhh, Bpe);
  pack_dec_k<<<64 * KID32, 64, 0, stream>>>(dWih, dWhh, Wo, Bpd);
  pack_wo_k<<<8 * KID, 64, 0, stream>>>(Wo, Bpw);
  bias_k<<<8, 256, 0, stream>>>(ebih, ebhh, dbih, dbhh, dWih, bo, benc, bdec);
  pack_x_k<<<16384, 256, 0, stream>>>(ts, xp);
  init_k<<<256, 256, 0, stream>>>((unsigned long long*)Hg, flgA, flgB, xcdP);

  lstm_persist<<<NWG, 512, 0, stream>>>(xp, Bpe, Bpd, Bpw, benc, bdec, bo, Hg,
                                        flgA, flgB, xcdP, outp);
}

// Round 8
// 1646.053 us; speedup vs baseline: 4.1724x; 1.0585x over previous
//
#include <hip/hip_runtime.h>

#define Bn 512
#define Tn 256
#define Fn 128
#define Hn 512
#define KIE32 40  // 640/16 k-iters (encoder, 32x32x16)
#define KID32 32  // 512/16 k-iters (decoder)
#define EH 20     // enc k-iters per wave (k-split half)
#define DH 16     // dec k-iters per wave
#define KID 16    // y-path: 512/32 k-iters (16x16x32)
#define NWG 256
#define RS 648    // A_lds row stride in ushorts (16B-aligned)

typedef __attribute__((ext_vector_type(8))) __bf16 bf16x8;
typedef __attribute__((ext_vector_type(4))) float floatx4;
typedef __attribute__((ext_vector_type(16))) float floatx16;
typedef __attribute__((ext_vector_type(4))) unsigned uintx4;

__device__ __forceinline__ unsigned short f2bf_u16(float f) {
  union { float f; unsigned u; } v; v.f = f;
  unsigned r = v.u + 0x7FFFu + ((v.u >> 16) & 1u);   // RNE
  return (unsigned short)(r >> 16);
}

__device__ __forceinline__ float sigm(float x) {
  return __builtin_amdgcn_rcpf(1.f + __expf(-x));
}
__device__ __forceinline__ float ftanh(float x) {
  return 1.f - 2.f * __builtin_amdgcn_rcpf(1.f + __expf(2.f * x));
}

// ---- pack encoder weights [x|h] -> 32x32x16 B-fragment order ----
__global__ void pack_enc_k(const float* __restrict__ Wih, const float* __restrict__ Whh,
                           unsigned short* __restrict__ Bpe) {
  int id = blockIdx.x;              // nt32*KIE32 + ki
  int nt = id / KIE32, ki = id % KIE32;
  int l = threadIdx.x;
  int n = nt * 32 + (l & 31);
  int kb = ki * 16 + (l >> 5) * 8;
  __align__(16) unsigned short o[8];
#pragma unroll
  for (int j = 0; j < 8; ++j) {
    int k = kb + j;
    float v = (k < Fn) ? Wih[n * Fn + k] : Whh[n * Hn + (k - Fn)];
    o[j] = f2bf_u16(v);
  }
  *(uint4*)(Bpe + (size_t)(id * 64 + l) * 8) = *(uint4*)o;
}

// ---- pack decoder combined weights (W_hh + W_ih@Wo) -> 32x32 frag order ----
__global__ void pack_dec_k(const float* __restrict__ Wih, const float* __restrict__ Whh,
                           const float* __restrict__ Wo, unsigned short* __restrict__ Bpd) {
  int id = blockIdx.x;              // nt32*KID32 + ki
  int nt = id / KID32, ki = id % KID32;
  int l = threadIdx.x;
  int n = nt * 32 + (l & 31);
  int kb = ki * 16 + (l >> 5) * 8;
  float acc[8];
#pragma unroll
  for (int j = 0; j < 8; ++j) acc[j] = Whh[n * Hn + kb + j];
  for (int f = 0; f < Fn; ++f) {
    float wf = Wih[n * Fn + f];
    const float* wo = Wo + f * Hn + kb;
#pragma unroll
    for (int j = 0; j < 8; ++j) acc[j] += wf * wo[j];
  }
  __align__(16) unsigned short o[8];
#pragma unroll
  for (int j = 0; j < 8; ++j) o[j] = f2bf_u16(acc[j]);
  *(uint4*)(Bpd + (size_t)(id * 64 + l) * 8) = *(uint4*)o;
}

// ---- pack Wo (y = h@Wo.T) -> 16x16x32 fragment order ----
__global__ void pack_wo_k(const float* __restrict__ Wo, unsigned short* __restrict__ Bpw) {
  int id = blockIdx.x;              // ft*KID + ki
  int ft = id / KID, ki = id % KID;
  int l = threadIdx.x;
  int f = ft * 16 + (l & 15);
  int kb = ki * 32 + (l >> 4) * 8;
  __align__(16) unsigned short o[8];
#pragma unroll
  for (int j = 0; j < 8; ++j) o[j] = f2bf_u16(Wo[f * Hn + kb + j]);
  *(uint4*)(Bpw + (size_t)(id * 64 + l) * 8) = *(uint4*)o;
}

// ---- biases ----
__global__ void bias_k(const float* __restrict__ ebih, const float* __restrict__ ebhh,
                       const float* __restrict__ dbih, const float* __restrict__ dbhh,
                       const float* __restrict__ dWih, const float* __restrict__ bo,
                       float* __restrict__ benc, float* __restrict__ bdec) {
  int n = blockIdx.x * blockDim.x + threadIdx.x;  // 2048
  benc[n] = ebih[n] + ebhh[n];
  float a = dbih[n] + dbhh[n];
  for (int f = 0; f < Fn; ++f) a += dWih[n * Fn + f] * bo[f];
  bdec[n] = a;
}

// ---- pack x: ts[b][s][k] fp32 -> xp[s][b][k] bf16 ----
__global__ void pack_x_k(const float* __restrict__ ts, unsigned short* __restrict__ xp) {
  size_t i = (size_t)blockIdx.x * 256 + threadIdx.x;   // quad index
  int k4 = (int)(i & 31);
  size_t bs = i >> 5;
  int s = (int)(bs & 255);
  size_t b = bs >> 8;
  float4 v = *(const float4*)(ts + (i << 2));
  __align__(8) unsigned short o[4];
  o[0] = f2bf_u16(v.x); o[1] = f2bf_u16(v.y); o[2] = f2bf_u16(v.z); o[3] = f2bf_u16(v.w);
  *(unsigned long long*)(xp + ((size_t)s * Bn + b) * Fn + k4 * 4) = *(unsigned long long*)o;
}

// ---- init: zero Hg buffer 0 + flags + XCC sentinels ----
__global__ void init_k(unsigned long long* __restrict__ Hg0,
                       unsigned* __restrict__ flgA, unsigned* __restrict__ flgB,
                       unsigned* __restrict__ xcdP) {
  int i = blockIdx.x * 256 + threadIdx.x;   // 65536
  Hg0[i] = 0ULL;
  if (i < 8192) { flgA[i] = 0u; flgB[i] = 0u; }
  if (i < NWG) xcdP[i] = 0xFFu;             // sentinel (overlays out[0..255])
}

// Flag protocol: PROVEN baseline only (sc1 / LLC, agent scope).
#define POLL(F, p) do { \
  if (l < 16) { \
    const unsigned* fp_ = (F) + (size_t)(mg * 16 + l) * 32; \
    while (__hip_atomic_load(fp_, __ATOMIC_RELAXED, __HIP_MEMORY_SCOPE_AGENT) < (unsigned)(p)) \
      __builtin_amdgcn_s_sleep(1); \
  } \
  __asm__ __volatile__("" ::: "memory"); \
} while (0)

#define SETF(F, p) do { if (tid == 0) \
  __hip_atomic_store((F) + (size_t)gid * 32, (unsigned)(p), __ATOMIC_RELAXED, __HIP_MEMORY_SCOPE_AGENT); \
} while (0)

// h loads, 32 rows, 64B/thread: loc==1 -> sc0 (this XCD's L2); else sc1.
#define STAGE_H2(OFF, curbuf) do { \
  const unsigned short* sp_ = Hg + (size_t)(curbuf) * (Bn * Hn) + (size_t)(b0 + sh_r) * Hn + sh_c * 32; \
  uintx4 t0_, t1_, t2_, t3_; \
  if (loc) { \
    asm volatile("global_load_dwordx4 %0, %4, off sc0\n\t" \
                 "global_load_dwordx4 %1, %4, off offset:16 sc0\n\t" \
                 "global_load_dwordx4 %2, %4, off offset:32 sc0\n\t" \
                 "global_load_dwordx4 %3, %4, off offset:48 sc0\n\t" \
                 "s_waitcnt vmcnt(0)" \
                 : "=&v"(t0_), "=&v"(t1_), "=&v"(t2_), "=&v"(t3_) : "v"(sp_) : "memory"); \
  } else { \
    const unsigned long long* src_ = (const unsigned long long*)sp_; \
    unsigned long long v_[8]; \
    _Pragma("unroll") for (int u_ = 0; u_ < 8; ++u_) \
      v_[u_] = __hip_atomic_load(src_ + u_, __ATOMIC_RELAXED, __HIP_MEMORY_SCOPE_AGENT); \
    t0_[0] = (unsigned)v_[0]; t0_[1] = (unsigned)(v_[0] >> 32); t0_[2] = (unsigned)v_[1]; t0_[3] = (unsigned)(v_[1] >> 32); \
    t1_[0] = (unsigned)v_[2]; t1_[1] = (unsigned)(v_[2] >> 32); t1_[2] = (unsigned)v_[3]; t1_[3] = (unsigned)(v_[3] >> 32); \
    t2_[0] = (unsigned)v_[4]; t2_[1] = (unsigned)(v_[4] >> 32); t2_[2] = (unsigned)v_[5]; t2_[3] = (unsigned)(v_[5] >> 32); \
    t3_[0] = (unsigned)v_[6]; t3_[1] = (unsigned)(v_[6] >> 32); t3_[2] = (unsigned)v_[7]; t3_[3] = (unsigned)(v_[7] >> 32); \
  } \
  uintx4* dst_ = (uintx4*)&A_lds[sh_r * RS + (OFF) + sh_c * 32]; \
  dst_[0] = t0_; dst_[1] = t1_; dst_[2] = t2_; dst_[3] = t3_; \
} while (0)

// decoder y (16x16x32), dual accumulator chains
#define MFMA_Y(sd) do { \
  floatx4 ay0_ = {0.f, 0.f, 0.f, 0.f}, ay1_ = {0.f, 0.f, 0.f, 0.f}; \
  const unsigned short* Ay_ = &A_lds[(l15 + yro) * RS + q * 8]; \
  _Pragma("unroll") for (int k = 0; k < KID; k += 2) { \
    ay0_ = __builtin_amdgcn_mfma_f32_16x16x32_bf16( \
        *(const bf16x8*)(Ay_ + k * 32), *(const bf16x8*)&Bw_lds[(k * 64 + l) * 8], ay0_, 0, 0, 0); \
    ay1_ = __builtin_amdgcn_mfma_f32_16x16x32_bf16( \
        *(const bf16x8*)(Ay_ + (k + 1) * 32), *(const bf16x8*)&Bw_lds[((k + 1) * 64 + l) * 8], ay1_, 0, 0, 0); \
  } \
  _Pragma("unroll") for (int r = 0; r < 4; ++r) \
    __builtin_nontemporal_store(ay0_[r] + ay1_[r] + bof, \
      out + ((size_t)(b0 + yro + q * 4 + r) * Tn + (Tn - 1 - (sd))) * Fn + ns * 16 + l15); \
} while (0)

// 32x32x16 gate MFMA, dual independent accumulator chains (even/odd k).
// Each k-half wave stores its summed partial into its OWN buffer half —
// no atomics, no RMW pass, no mid-barrier. EPI adds the two halves.
#define GATES32(BR, KN) do { \
  floatx16 aE_ = {0.f}, aO_ = {0.f}; \
  const unsigned short* Ar_ = &A_lds[l31 * RS + (kh * (KN)) * 16 + ksub]; \
  _Pragma("unroll") for (int t = 0; t < (KN); t += 2) { \
    aE_ = __builtin_amdgcn_mfma_f32_32x32x16_bf16(*(const bf16x8*)(Ar_ + t * 16), (BR)[t], aE_, 0, 0, 0); \
    aO_ = __builtin_amdgcn_mfma_f32_32x32x16_bf16(*(const bf16x8*)(Ar_ + (t + 1) * 16), (BR)[t + 1], aO_, 0, 0, 0); \
  } \
  _Pragma("unroll") for (int r = 0; r < 16; ++r) \
    gates_lds[kh][g2][(r & 3) + 8 * (r >> 2) + 4 * lhi][l31] = aE_[r] + aO_[r]; \
} while (0)

// epilogue: 2 rows/thread (eb -> cA, eb+16 -> cB), col ej; sums both k-halves
#define EPI2(BI, BF, BG, BO, nxtbuf) do { \
  float gi0_ = gates_lds[0][0][eb][ej] + gates_lds[1][0][eb][ej] + (BI); \
  float gf0_ = gates_lds[0][1][eb][ej] + gates_lds[1][1][eb][ej] + (BF); \
  float gg0_ = gates_lds[0][2][eb][ej] + gates_lds[1][2][eb][ej] + (BG); \
  float go0_ = gates_lds[0][3][eb][ej] + gates_lds[1][3][eb][ej] + (BO); \
  float gi1_ = gates_lds[0][0][eb + 16][ej] + gates_lds[1][0][eb + 16][ej] + (BI); \
  float gf1_ = gates_lds[0][1][eb + 16][ej] + gates_lds[1][1][eb + 16][ej] + (BF); \
  float gg1_ = gates_lds[0][2][eb + 16][ej] + gates_lds[1][2][eb + 16][ej] + (BG); \
  float go1_ = gates_lds[0][3][eb + 16][ej] + gates_lds[1][3][eb + 16][ej] + (BO); \
  cA = sigm(gf0_) * cA + sigm(gi0_) * ftanh(gg0_); \
  float h0_ = sigm(go0_) * ftanh(cA); \
  cB = sigm(gf1_) * cB + sigm(gi1_) * ftanh(gg1_); \
  float h1_ = sigm(go1_) * ftanh(cB); \
  unsigned short hv0_ = f2bf_u16(h0_), hv1_ = f2bf_u16(h1_); \
  unsigned short* hp0_ = Hg + (size_t)(nxtbuf) * (Bn * Hn) + (size_t)(b0 + eb) * Hn + j0 + ej; \
  unsigned short* hp1_ = hp0_ + 16 * Hn; \
  if (loc) { *hp0_ = hv0_; *hp1_ = hv1_; } \
  else { \
    __hip_atomic_store(hp0_, hv0_, __ATOMIC_RELAXED, __HIP_MEMORY_SCOPE_AGENT); \
    __hip_atomic_store(hp1_, hv1_, __ATOMIC_RELAXED, __HIP_MEMORY_SCOPE_AGENT); \
  } \
} while (0)

// ---- persistent LSTM enc-dec: 256 wgs x 512 thr, 32x32x16 gate MFMA ----
// 3 barriers/step: staged | gates stored (both halves) | h drained.
__global__ __launch_bounds__(512, 1) void lstm_persist(
    const unsigned short* __restrict__ xp,
    const unsigned short* __restrict__ Bpe,
    const unsigned short* __restrict__ Bpd,
    const unsigned short* __restrict__ Bpw,
    const float* __restrict__ benc,
    const float* __restrict__ bdec,
    const float* __restrict__ bo,
    unsigned short* __restrict__ Hg,   // [2][512][512] bf16
    unsigned* __restrict__ flgA,
    unsigned* __restrict__ flgB,
    unsigned* __restrict__ xcdPub,     // [256] published XCC ids (overlays out)
    float* __restrict__ out)           // [512][256][128] fp32
{
  const int wg = blockIdx.x;
  const int tid = threadIdx.x;
  const int w = tid >> 6, l = tid & 63;
  const int l15 = l & 15, q = l >> 4;        // 16x16 y-path indices
  const int l31 = l & 31, lhi = l >> 5;      // 32x32 fragment indices
  const int g2 = w & 3, kh = w >> 2;         // wave = (gate, k-half)
  const int ksub = lhi * 8;                  // k sub-offset within k-iter
  const int eb = tid >> 5, ej = tid & 31;    // epilogue (rows eb, eb+16; col ej)
  const int sh_r = tid >> 4, sh_c = tid & 15;// staging (row 0..31, col chunk)

  // bijective relabel assuming round-robin XCD dispatch: XCD = wg & 7
  const int grp = wg & 7, rank = wg >> 3;
  const int mg = grp * 2 + (rank >> 4);
  const int ns = rank & 15;
  const int gid = mg * 16 + ns;
  const int b0 = mg * 32, j0 = ns * 32;

  __shared__ __align__(16) unsigned short A_lds[32 * RS];        // 41.5 KB
  __shared__ __align__(16) float gates_lds[2][4][32][33];        // 33.8 KB
  __shared__ __align__(16) unsigned short Bw_lds[KID * 64 * 8];  // 16.4 KB
  __shared__ int sh_asn[2];

  // ---- publish my XCC id; bounded group-local locality verification ----
  if (tid == 0) {
    unsigned x_;
    asm volatile("s_getreg_b32 %0, hwreg(HW_REG_XCC_ID)" : "=s"(x_));
    x_ &= 15u;
    sh_asn[1] = (int)x_;
    __hip_atomic_store(&xcdPub[wg], x_, __ATOMIC_RELAXED, __HIP_MEMORY_SCOPE_AGENT);
  }
  __syncthreads();
  const unsigned myx = (unsigned)sh_asn[1];
  if (tid < 64) {
    int ok = 1;
    if (tid < 16) {
      const int phys = grp + 8 * ((mg & 1) * 16 + tid);
      unsigned v_ = 0xFFu;
      for (int it = 0; it < 32768; ++it) {   // bounded: cannot hang
        v_ = __hip_atomic_load(&xcdPub[phys], __ATOMIC_RELAXED, __HIP_MEMORY_SCOPE_AGENT);
        if (v_ != 0xFFu) break;
        __builtin_amdgcn_s_sleep(2);
      }
      ok = (v_ == myx) ? 1 : 0;
    }
    int all_ = __all(ok) ? 1 : 0;
    if (tid == 0) sh_asn[0] = all_;
  }
  __syncthreads();
  const int loc = sh_asn[0];                 // group-uniform

  // ---- preload B tiles: (20+16)*4 = 144 regs ----
  bf16x8 Bq[EH], Bd[DH];
  const int nt32 = g2 * 16 + ns;
  {
    const bf16x8* p = (const bf16x8*)Bpe + ((size_t)nt32 * KIE32 + kh * EH) * 64 + l;
#pragma unroll
    for (int k = 0; k < EH; ++k) Bq[k] = p[k * 64];
  }
  {
    const bf16x8* p = (const bf16x8*)Bpd + ((size_t)nt32 * KID32 + kh * DH) * 64 + l;
#pragma unroll
    for (int k = 0; k < DH; ++k) Bd[k] = p[k * 64];
  }
  // per-thread gate biases (EPI uses col j0+ej)
  const float bie = benc[0 * Hn + j0 + ej], bfe = benc[1 * Hn + j0 + ej];
  const float bge = benc[2 * Hn + j0 + ej], boe = benc[3 * Hn + j0 + ej];
  const float bid = bdec[0 * Hn + j0 + ej], bfd = bdec[1 * Hn + j0 + ej];
  const float bgd = bdec[2 * Hn + j0 + ej], bod = bdec[3 * Hn + j0 + ej];

  if (ns < 8) { // constant Wo slice -> LDS, once
    const uint4* src = (const uint4*)(Bpw + (size_t)ns * (KID * 64 * 8));
    uint4* dst = (uint4*)Bw_lds;
    dst[tid * 2] = src[tid * 2];
    dst[tid * 2 + 1] = src[tid * 2 + 1];
  }
  const bool doY = (ns < 8) && (g2 == 3);    // waves 3 (kh0) and 7 (kh1)
  const int yro = kh ? 16 : 0;
  float bof = 0.f;
  if (doY) bof = bo[ns * 16 + l15];

  float cA = 0.f, cB = 0.f;

  __syncthreads();                   // Bw_lds staged

  // ================= encoder =================
  for (int s = 0; s < Tn; ++s) {
    const int cur = s & 1, nxt = cur ^ 1;
    // x prefetch: pure input, independent of flags — issue before POLL
    uint4 xv_ = *(const uint4*)(xp + ((size_t)s * Bn + b0 + sh_r) * Fn + sh_c * 8);
    POLL(flgA, s);                   // all members: h(s-1) visible, buffers safe
    STAGE_H2(Fn, cur);
    *(uint4*)&A_lds[sh_r * RS + sh_c * 8] = xv_;
    __syncthreads();                 // A staged
    GATES32(Bq, EH);                 // dual chains; store partial to own half
    __syncthreads();                 // both halves stored
    EPI2(bie, bfe, bge, boe, nxt);
    __syncthreads();                 // drains EPI h stores (vmcnt0 at barrier)
    SETF(flgA, s + 1);
  }

  // ================= decoder =================
  cA = 0.f; cB = 0.f;                // reference restarts c at zero
  for (int sd = 0; sd < Tn; ++sd) {
    const int phg = Tn + sd;
    const int cur = phg & 1, nxt = cur ^ 1;
    POLL(flgA, phg);
    STAGE_H2(0, cur);
    __syncthreads();
    GATES32(Bd, DH);
    if (doY) MFMA_Y(sd);
    __syncthreads();
    EPI2(bid, bfd, bgd, bod, nxt);
    __syncthreads();
    SETF(flgA, phg + 1);
  }
}

extern "C" void kernel_launch(void* const* d_in, const int* in_sizes, int n_in,
                              void* d_out, int out_size, void* d_ws, size_t ws_size,
                              hipStream_t stream) {
  const float* ts   = (const float*)d_in[0];
  const float* eWih = (const float*)d_in[1];
  const float* eWhh = (const float*)d_in[2];
  const float* ebih = (const float*)d_in[3];
  const float* ebhh = (const float*)d_in[4];
  const float* dWih = (const float*)d_in[5];
  const float* dWhh = (const float*)d_in[6];
  const float* dbih = (const float*)d_in[7];
  const float* dbhh = (const float*)d_in[8];
  const float* Wo   = (const float*)d_in[9];
  const float* bo   = (const float*)d_in[10];
  float* outp = (float*)d_out;

  char* ws = (char*)d_ws;
  unsigned short* Bpe  = (unsigned short*)(ws);                 // 2,621,440 B
  unsigned short* Bpd  = (unsigned short*)(ws + 2621440);       // 2,097,152 B
  unsigned short* Bpw  = (unsigned short*)(ws + 4718592);       //   131,072 B
  float*          benc = (float*)(ws + 4849664);                //     8,192 B
  float*          bdec = (float*)(ws + 4857856);                //     8,192 B
  unsigned short* Hg   = (unsigned short*)(ws + 4866048);       // 1,048,576 B
  unsigned*       flgA = (unsigned*)(ws + 5914624);             //    32,768 B
  unsigned*       flgB = (unsigned*)(ws + 5947392);             //    32,768 B
  unsigned short* xp   = (unsigned short*)(ws + 5980160);       // 16,777,216 B
  unsigned*       xcdP = (unsigned*)outp;   // scratch overlay; decoder rewrites
                                            // out[0..255] only at sd>=254,
                                            // strictly after all reads of it

  pack_enc_k<<<64 * KIE32, 64, 0, stream>>>(eWih, eWhh, Bpe);
  pack_dec_k<<<64 * KID32, 64, 0, stream>>>(dWih, dWhh, Wo, Bpd);
  pack_wo_k<<<8 * KID, 64, 0, stream>>>(Wo, Bpw);
  bias_k<<<8, 256, 0, stream>>>(ebih, ebhh, dbih, dbhh, dWih, bo, benc, bdec);
  pack_x_k<<<16384, 256, 0, stream>>>(ts, xp);
  init_k<<<256, 256, 0, stream>>>((unsigned long long*)Hg, flgA, flgB, xcdP);

  lstm_persist<<<NWG, 512, 0, stream>>>(xp, Bpe, Bpd, Bpw, benc, bdec, bo, Hg,
                                        flgA, flgB, xcdP, outp);
}